// Round 7
// baseline (272.674 us; speedup 1.0000x reference)
//
#include <hip/hip_runtime.h>
#include <math.h>

// EqualtimeLayer R20: R13's resource envelope + R14's bucket-sum math +
// R19's bump-scatter and lazy validity. 4 barriers/batch, no solve loop.
//
// R19 post-mortem: wave-private needs 16 events/lane live -> 470MB scratch+
// re-read traffic. Only the block-coop EPT=4 layout fits 64 VGPRs (R13: 32).
// R20 pipeline per batch:
//  hist: per-event 3 fire-and-forget LDS atomics into bucket aggregates
//        {cnt, W=sum w, WT=sum w*t}; excluded-events min via wave reduce.
//  B1 -> scans IN PARALLEL: wave0 cnt->off<<12|cnt, wave1 W->excl prefix,
//        wave2 WT->excl prefix (each a 20-op int4/lane scan, R13-proven).
//  B2 -> scatter: atomicAdd(&pk[k],4096) returns position (R19-proven);
//        st/sw written in bucket order.
//  B3 -> candidates, fully thread-local (R14-proven exact): W = Wbase +
//        CW[k] + (earlier mates) + w_e; tmp=(theta+WT...)/W; valid iff
//        tmp>=t_e, tmp<=tnx (later mates), and tmp<=next-event time:
//        tmp<=edge(k+1) proves it arithmetically (bucket ranges ordered);
//        else exact lazy lookup of the next nonempty bucket's min (R19).
//        Meanwhile zero the OTHER aggregate buffer (ping-pong, R14).
//  B4 -> block min; next stage/batch uses the freshly zeroed buffer.
// Tail stage (no crossing among t<TCUT, rare): same machinery over
// [TCUT,2.0) with Wbase/WTbase = stage-0 scan totals. Exact.
// LDS 14.4KB -> 8 blocks/CU; launch_bounds(256,8). WRITE_SIZE = spill
// tripwire (fired R15/R18/R19; live set here ~= R13's + pos[4]).

#define B_TOT 32
#define PRE 1024
#define POST 1024
#define NB 256
#define TPB 256
#define EPT 4
#define BPW 8
#define TCUTF 0.625f
#define BSCALE 409.6f          // 256 buckets over [0, 0.625)
#define BSCALE2 186.18181818f  // 256 buckets over [0.625, 2.0)
#define INV1 0.00244140625f    // 1/409.6 (= 5/2048, exact)
#define INV2 0.00537109375f    // 1.375/256 (exact)
#define EDGEG 0.999998f        // conservative edge guard (under-accept only)

// ---- DPP helpers (gfx9 encodings; proven R13+) ----
template<int CTRL, int MASK>
__device__ __forceinline__ int dpp_add_i32(int v) {
    return v + __builtin_amdgcn_update_dpp(0, v, CTRL, MASK, 0xf, true);
}
template<int CTRL, int MASK>
__device__ __forceinline__ float dpp_add_f32(float v) {
    int t = __builtin_amdgcn_update_dpp(0, __float_as_int(v), CTRL, MASK, 0xf, true);
    return v + __int_as_float(t);
}
template<int CTRL>
__device__ __forceinline__ float dpp_min_f32(float v) {
    int t = __builtin_amdgcn_update_dpp(__float_as_int(v), __float_as_int(v), CTRL, 0xf, 0xf, false);
    return fminf(v, __int_as_float(t));
}
__device__ __forceinline__ int wave_iscan_i32(int v) {
    v = dpp_add_i32<0x111, 0xf>(v);
    v = dpp_add_i32<0x112, 0xf>(v);
    v = dpp_add_i32<0x114, 0xf>(v);
    v = dpp_add_i32<0x118, 0xf>(v);
    v = dpp_add_i32<0x142, 0xa>(v);
    v = dpp_add_i32<0x143, 0xc>(v);
    return v;
}
__device__ __forceinline__ float wave_iscan_f32(float v) {
    v = dpp_add_f32<0x111, 0xf>(v);
    v = dpp_add_f32<0x112, 0xf>(v);
    v = dpp_add_f32<0x114, 0xf>(v);
    v = dpp_add_f32<0x118, 0xf>(v);
    v = dpp_add_f32<0x142, 0xa>(v);
    v = dpp_add_f32<0x143, 0xc>(v);
    return v;
}
__device__ __forceinline__ float wave_min_f32(float v) {
    v = fminf(v, __shfl_down(v, 32));
    v = fminf(v, __shfl_down(v, 16));
    v = dpp_min_f32<0x140>(v);
    v = dpp_min_f32<0x141>(v);
    v = dpp_min_f32<0x4E>(v);
    v = dpp_min_f32<0xB1>(v);
    return v;
}

// Wave-0: exclusive scan of 256 counts in place -> off<<12|cnt; total->*ntot.
__device__ __forceinline__ void scan_pck(int* arr, int* ntot, int lane) {
    int4 a = reinterpret_cast<int4*>(arr)[lane];
    int c[4] = {a.x, a.y, a.z, a.w};
    int le[4]; int s = 0;
#pragma unroll
    for (int j = 0; j < 4; ++j) { le[j] = s; s += c[j]; }
    int x = wave_iscan_i32(s);
    int e = x - s;
    reinterpret_cast<int4*>(arr)[lane] =
        make_int4(((e + le[0]) << 12) | c[0], ((e + le[1]) << 12) | c[1],
                  ((e + le[2]) << 12) | c[2], ((e + le[3]) << 12) | c[3]);
    if (lane == 63) *ntot = x;
}
// Waves 1/2: exclusive f32 scan of 256 sums in place; total -> *tot.
__device__ __forceinline__ void scan_f32(float* arr, float* tot, int lane) {
    float4 a = reinterpret_cast<float4*>(arr)[lane];
    float c[4] = {a.x, a.y, a.z, a.w};
    float le[4]; float s = 0.f;
#pragma unroll
    for (int j = 0; j < 4; ++j) { le[j] = s; s += c[j]; }
    float x = wave_iscan_f32(s);
    float e = x - s;
    reinterpret_cast<float4*>(arr)[lane] =
        make_float4(e + le[0], e + le[1], e + le[2], e + le[3]);
    if (lane == 63) *tot = x;
}

// Thread-local candidate (R14 sums + R19 lazy validity; both proven exact).
__device__ __forceinline__ float cand_eval(
    const float* st, const float* sw, const int* PK,
    const float* CW, const float* CWT,
    float t_e, float w_e, int p0, int k,
    float t0, float scl, float inv, int Ntot, float tEnd,
    float theta, float Wb, float WTb)
{
    int v = PK[k];                       // post-bump: (off+cnt)<<12 | cnt
    int cn = v & 0xfff;
    int end = v >> 12;
    int bas = end - cn;
    float iw = 0.f, iwt = 0.f, tnx = INFINITY;
    if (cn > 1) {
        for (int q = bas; q < end; ++q) {
            if (q == p0) continue;
            float tq = st[q], wq = sw[q];
            bool earlier = (tq < t_e) || (tq == t_e && q < p0);
            if (earlier) { iw += wq; iwt += wq * tq; }
            else tnx = fminf(tnx, tq);
        }
    }
    float W = Wb + CW[k] + iw + w_e;
    if (!(W > 0.f)) return INFINITY;
    float tmp = (theta + WTb + CWT[k] + iwt + w_e * t_e) * __builtin_amdgcn_rcpf(W);
    if (tmp < t_e || tmp > tnx) return INFINITY;
    // bucket ranges are disjoint+ordered: tmp <= edge(k+1) (guarded down)
    // proves tmp <= every later-bucket event time.
    float edge = t0 + (float)(k + 1) * inv * EDGEG;
    if (tmp <= edge) return tmp;
    float cross;
    if (end >= Ntot) cross = tEnd;       // no later in-stage event
    else {
        float t1 = st[end];              // member of next nonempty bucket
        int k2 = (int)((t1 - t0) * scl);
        k2 = k2 > NB - 1 ? NB - 1 : k2;
        int v2 = PK[k2];
        int cn2 = v2 & 0xfff;
        int b2 = (v2 >> 12) - cn2;
        cross = t1;
        for (int q = b2; q < b2 + cn2; ++q) cross = fminf(cross, st[q]);
    }
    return (tmp <= cross) ? tmp : INFINITY;
}

// One stage. PK/CW/CWT must be zeroed at entry; the OTHER buffer
// (PKo/CWo/CWTo) is zeroed here for the next stage. 4 barriers.
template<bool COLLECT_EXCL>
__device__ __forceinline__ float do_stage(
    float* st, float* sw,
    int* PK, float* CW, float* CWT,
    int* PKo, float* CWo, float* CWTo,
    const float (&tv)[EPT], const float (&wg)[EPT], const int (&kb)[EPT],
    float t0, float scl, float inv,
    float Wb, float WTb, float theta,
    int* s_n, float* s_tw, float* s_red,
    int tid, int lane, int wid,
    int& NtotOut, float& totWOut, float& totWTOut)
{
    // ---- hist: 3 fire-and-forget LDS atomics per included event ----
    float mloc = INFINITY;
#pragma unroll
    for (int j = 0; j < EPT; ++j) {
        int k = kb[j];
        if (k >= 0) {
            atomicAdd(&PK[k], 1);
            atomicAdd(&CW[k], wg[j]);
            atomicAdd(&CWT[k], wg[j] * tv[j]);
        } else if (COLLECT_EXCL) {
            mloc = fminf(mloc, tv[j]);
        }
    }
    __syncthreads();                                   // B1: aggregates final
    if (COLLECT_EXCL) {
        mloc = wave_min_f32(mloc);
        if (lane == 0) s_red[wid] = mloc;              // post-B1 write, post-B2 read
    }
    if (wid == 0)      scan_pck(PK, s_n, lane);
    else if (wid == 1) scan_f32(CW, s_tw + 0, lane);
    else if (wid == 2) scan_f32(CWT, s_tw + 1, lane);
    __syncthreads();                                   // B2: scans visible

    const int Ntot = *s_n;
    NtotOut = Ntot;
    totWOut = s_tw[0];
    totWTOut = s_tw[1];
    float tEnd = INFINITY;
    if (COLLECT_EXCL)
        tEnd = fminf(fminf(s_red[0], s_red[1]), fminf(s_red[2], s_red[3]));

    // ---- scatter: atomic bump of offset field returns position ----
    int pos[EPT];
#pragma unroll
    for (int j = 0; j < EPT; ++j) {
        if (kb[j] >= 0) {
            int old = atomicAdd(&PK[kb[j]], 4096);
            int p = old >> 12;
            st[p] = tv[j];
            sw[p] = wg[j];
            pos[j] = p;
        }
    }
    __syncthreads();                                   // B3: scatter visible

    // ---- thread-local candidates + zero other buffer ----
    float mc = INFINITY;
#pragma unroll
    for (int j = 0; j < EPT; ++j) {
        if (kb[j] >= 0)
            mc = fminf(mc, cand_eval(st, sw, PK, CW, CWT, tv[j], wg[j],
                                     pos[j], kb[j], t0, scl, inv,
                                     Ntot, tEnd, theta, Wb, WTb));
    }
    PKo[tid] = 0; CWo[tid] = 0.f; CWTo[tid] = 0.f;     // NB == TPB
    mc = wave_min_f32(mc);
    if (lane == 0) s_red[wid] = mc;
    __syncthreads();                                   // B4: mins + zero visible
    return fminf(fminf(s_red[0], s_red[1]), fminf(s_red[2], s_red[3]));
}

__global__ __launch_bounds__(TPB, 8) void equaltime_kernel(
    const float* __restrict__ spikes,     // [B][PRE]
    const float* __restrict__ weights,    // [PRE][POST]
    const float* __restrict__ delays,     // [PRE][POST]
    const float* __restrict__ thresholds, // [POST]
    float* __restrict__ out)              // [B][POST]
{
    __shared__ __align__(16) float s_t[PRE];        // 4 KB scattered times
    __shared__ __align__(16) float s_w[PRE];        // 4 KB scattered weights
    __shared__ __align__(16) int   s_pk[2][NB];     // 2 KB cnt -> off<<12|cnt
    __shared__ __align__(16) float s_cw[2][NB];     // 2 KB W sums -> excl prefix
    __shared__ __align__(16) float s_cwt[2][NB];    // 2 KB WT sums -> excl prefix
    __shared__ float s_red[4];
    __shared__ float s_tw[2];
    __shared__ int   s_n;

    const int tid  = threadIdx.x;
    const int lane = tid & 63;
    const int wid  = tid >> 6;

    // XCD-contiguous swizzle for weight/delay L2 locality
    const int bx   = blockIdx.x;
    const int sbx  = (bx & 7) * 512 + (bx >> 3);
    const int post = sbx >> 2;            // 4 WGs per post
    const int b0   = (sbx & 3) * BPW;
    const float theta = thresholds[post];

    float dly[EPT], wgt[EPT];
#pragma unroll
    for (int j = 0; j < EPT; ++j) {
        int pre = tid * EPT + j;
        dly[j] = delays[pre * POST + post];
        wgt[j] = weights[pre * POST + post];
    }

    // init both aggregate buffers (NB == TPB: one element per thread each)
    s_pk[0][tid] = 0;  s_pk[1][tid] = 0;
    s_cw[0][tid] = 0.f; s_cw[1][tid] = 0.f;
    s_cwt[0][tid] = 0.f; s_cwt[1][tid] = 0.f;
    __syncthreads();

    int pb = 0;
    for (int bi = 0; bi < BPW; ++bi) {
        const int b = b0 + bi;
        float4 sp = *reinterpret_cast<const float4*>(spikes + b * PRE + tid * EPT);
        float tv[EPT] = {sp.x + dly[0], sp.y + dly[1], sp.z + dly[2], sp.w + dly[3]};
        int kb[EPT];
#pragma unroll
        for (int j = 0; j < EPT; ++j) {
            int k = (int)(tv[j] * BSCALE);
            kb[j] = (k < NB) ? k : -1;             // -1 => tail event
        }

        int Nlow; float totW, totWT;
        float mAll = do_stage<true>(
            s_t, s_w, s_pk[pb], s_cw[pb], s_cwt[pb],
            s_pk[pb ^ 1], s_cw[pb ^ 1], s_cwt[pb ^ 1],
            tv, wgt, kb, 0.f, BSCALE, INV1,
            0.f, 0.f, theta, &s_n, s_tw, s_red,
            tid, lane, wid, Nlow, totW, totWT);
        pb ^= 1;

        // rare exact fallback: no valid crossing among t < TCUT
        if (!(mAll < INFINITY) && Nlow < PRE) {
#pragma unroll
            for (int j = 0; j < EPT; ++j) {
                int k = (int)(tv[j] * BSCALE);
                if (k >= NB) {
                    int k2 = (int)((tv[j] - TCUTF) * BSCALE2);
                    kb[j] = k2 > NB - 1 ? NB - 1 : (k2 < 0 ? 0 : k2);
                } else {
                    kb[j] = -1;
                }
            }
            int d1; float d2, d3;
            mAll = do_stage<false>(
                s_t, s_w, s_pk[pb], s_cw[pb], s_cwt[pb],
                s_pk[pb ^ 1], s_cw[pb ^ 1], s_cwt[pb ^ 1],
                tv, wgt, kb, TCUTF, BSCALE2, INV2,
                totW, totWT, theta, &s_n, s_tw, s_red,
                tid, lane, wid, d1, d2, d3);
            pb ^= 1;
        }

        if (tid == 0) out[b * POST + post] = mAll;
        // No trailing barrier: next batch's hist atomics target the buffer
        // zeroed before B4 of this stage (barrier-ordered); s_red next write
        // is post-B1 of the next stage (barrier-ordered after our B4 reads).
    }
}

extern "C" void kernel_launch(void* const* d_in, const int* in_sizes, int n_in,
                              void* d_out, int out_size, void* d_ws, size_t ws_size,
                              hipStream_t stream) {
    const float* spikes     = (const float*)d_in[0]; // [32,1024]
    const float* weights    = (const float*)d_in[1]; // [1024,1024]
    const float* delays     = (const float*)d_in[2]; // [1024,1024]
    const float* thresholds = (const float*)d_in[3]; // [1024]
    float* outp = (float*)d_out;                     // [32,1024]

    dim3 grid(POST * (B_TOT / BPW)); // 4096 workgroups
    dim3 block(TPB);
    equaltime_kernel<<<grid, block, 0, stream>>>(spikes, weights, delays, thresholds, outp);
}